// Round 13
// baseline (142.081 us; speedup 1.0000x reference)
//
#include <hip/hip_runtime.h>

#define T_TOK 2048
#define HID   2048
#define NH    16
#define NKV   2
#define HD    128
#define QDIM  (NH * HD)                 // 2048
#define KVDIM (NKV * HD)                // 256
#define QKVDIM (QDIM + 2 * KVDIM)       // 2560

typedef float          f32x4  __attribute__((ext_vector_type(4)));
typedef unsigned short u16x8  __attribute__((ext_vector_type(8)));
typedef __bf16         bf16x8 __attribute__((ext_vector_type(8)));

__device__ __forceinline__ unsigned short f2bf(float f) {
    __bf16 h = (__bf16)f;
    return __builtin_bit_cast(unsigned short, h);
}

__device__ __forceinline__ f32x4 mfma16(u16x8 a, u16x8 b, f32x4 c) {
    return __builtin_amdgcn_mfma_f32_16x16x32_bf16(
        __builtin_bit_cast(bf16x8, a), __builtin_bit_cast(bf16x8, b), c, 0, 0, 0);
}

#define QSCL 0.12751743f        // 128^-0.5 * log2(e)
#define DEFER_THR 11.5416f      // defer-max threshold (log2 units)

// ---------------------------------------------------------------------------
// Workspace layout (ws >= 64 MB):
//   hb   [0,        8388608)   bf16 hidden   (dead after qkv_gemm)
//   Wf   [8388608, 18874368)   bf16 fused W  (dead after qkv_gemm)
//   ctab [18874368,19922944)   fp32 cos|sin  (dead after qkv_gemm)
//   qr   [19922944,28311552)
//   kr   [28311552,29360128)
//   vt   [29360128,30408704)
//   att  [30408704,38797312)
//   Wob  [38797312,47185920)
//   pO slots 0-575  [47185920,66060288); slots 576-831 alias hb [0,8388608)
//   pML  [66060288,66486272)
// ---------------------------------------------------------------------------
__device__ __forceinline__ float* slotO(char* b, int s) {
    return (float*)(s < 576 ? b + 47185920 + (size_t)s * 32768
                            : b + (size_t)(s - 576) * 32768);
}
#define PML_OFF 66060288

// Split-K schedule, LPT order (longest chunks first). 63 entries per head.
// Tiles tau<=10 whole (SLT=255 -> direct write); tau 11-21 2 chunks;
// tau 22-31 3 chunks. kcnt = CNT, kstart = CST (in 64-key blocks).
// slot-in-head = SLT (tau 11-21: (tau-11)*2+ci; tau 22-31: 22+(tau-22)*3+ci).
__device__ const unsigned char S_TAU[63] = {
 10,20,21,21,30,31,31,
  9,18,19,19,20,27,28,28,29,29,29,30,30,31,
  8,16,17,17,18,24,25,25,26,26,26,27,27,28,
  7,14,15,15,16,22,22,23,23,23,24,24,25,
  6,12,13,13,14,22,
  5,11,11,12,
  4,3,2,1,0 };
__device__ const unsigned char S_CST[63] = {
  0,0,0,11,0,0,11,
  0,0,0,10,11,0,0,10,0,10,20,11,21,22,
  0,0,0,9,10,0,0,9,0,9,18,10,19,20,
  0,0,0,8,9,0,8,0,8,16,9,17,18,
  0,0,0,7,8,16,
  0,0,6,7,
  0,0,0,0,0 };
__device__ const unsigned char S_CNT[63] = {
 11,11,11,11,11,11,11,
 10,10,10,10,10,10,10,10,10,10,10,10,10,10,
  9,9,9,9,9,9,9,9,9,9,9,9,9,9,
  8,8,8,8,8,8,8,8,8,8,8,8,8,
  7,7,7,7,7,7,
  6,6,6,6,
  5,4,3,2,1 };
__device__ const unsigned char S_SLT[63] = {
 255,18,20,21,46,49,50,
 255,14,16,17,19,37,40,41,43,44,45,47,48,51,
 255,10,12,13,15,28,31,32,34,35,36,38,39,42,
 255,6,8,9,11,22,23,25,26,27,29,30,33,
 255,2,4,5,7,24,
 255,0,1,3,
 255,255,255,255,255 };

// ---------------------------------------------------------------------------
// K0: fp32->bf16 packs (blocks 0..6655) + RoPE cos/sin table (6656..7167).
// ---------------------------------------------------------------------------
__global__ __launch_bounds__(256) void pack_bf16_all(
    const float* __restrict__ hidden, const float* __restrict__ Wq,
    const float* __restrict__ Wk, const float* __restrict__ Wv,
    const float* __restrict__ Wo, const int* __restrict__ positions,
    unsigned short* __restrict__ hb, unsigned short* __restrict__ Wf,
    unsigned short* __restrict__ Wob, float* __restrict__ ctab)
{
    const int b = blockIdx.x;
    if (b >= 6656) {
        const int bb = b - 6656;                 // 0..511
        const int t  = bb * 4 + (threadIdx.x >> 6);
        const int j  = threadIdx.x & 63;
        float invf = expf(-(float)j * 0.14391156831212787f);  // 10000^(-j/64)
        float f = (float)positions[t] * invf;
        ctab[(size_t)t * 128 + j]      = cosf(f);
        ctab[(size_t)t * 128 + 64 + j] = sinf(f);
        return;
    }
    const float* src; unsigned short* dst; size_t off;
    if      (b < 2048) { src = hidden; dst = hb;            off = (size_t)b * 2048; }
    else if (b < 4096) { src = Wq;     dst = Wf;            off = (size_t)(b - 2048) * 2048; }
    else if (b < 4352) { src = Wk;     dst = Wf + 4194304;  off = (size_t)(b - 4096) * 2048; }
    else if (b < 4608) { src = Wv;     dst = Wf + 4718592;  off = (size_t)(b - 4352) * 2048; }
    else               { src = Wo;     dst = Wob;           off = (size_t)(b - 4608) * 2048; }

    const size_t i = off + threadIdx.x * 8;
    float4 f0 = *reinterpret_cast<const float4*>(src + i);
    float4 f1 = *reinterpret_cast<const float4*>(src + i + 4);
    u16x8 o;
    o[0]=f2bf(f0.x); o[1]=f2bf(f0.y); o[2]=f2bf(f0.z); o[3]=f2bf(f0.w);
    o[4]=f2bf(f1.x); o[5]=f2bf(f1.y); o[6]=f2bf(f1.z); o[7]=f2bf(f1.w);
    *reinterpret_cast<u16x8*>(dst + i) = o;
}

// ---------------------------------------------------------------------------
// K1a: fused QKV GEMM. 64x128 tile, BK=64, dbuf global_load_lds + counted
// vmcnt(6), XCD swizzle. Epilogue fuses RoPE (q pre-scaled by QSCL) and
// V-transpose.
// ---------------------------------------------------------------------------
__global__ __launch_bounds__(256) void qkv_gemm_fused(
    const unsigned short* __restrict__ A,   // hb  bf16 [2048][2048]
    const unsigned short* __restrict__ B,   // Wf  bf16 [2560][2048]
    const float* __restrict__ ctab,         // [T][128] cos|sin
    unsigned short* __restrict__ qr,        // bf16 [T][QDIM], pre-scaled
    unsigned short* __restrict__ kr,        // bf16 [T][KVDIM]
    unsigned short* __restrict__ vt)        // bf16 [KVDIM][T]
{
    __shared__ alignas(16) char smem[49152];
    unsigned short* AsBase = (unsigned short*)smem;           // [2][4096]
    unsigned short* BsBase = (unsigned short*)(smem + 16384); // [2][8192]

    const int tid  = threadIdx.x;
    const int lane = tid & 63;
    const int w    = tid >> 6;
    const int lg   = lane >> 4, lc = lane & 15;

    const int nbx = QKVDIM / 128;            // 20
    const int cpx = gridDim.x >> 3;
    const int wg  = (blockIdx.x & 7) * cpx + (blockIdx.x >> 3);
    const int m0  = (wg / nbx) * 64, n0 = (wg % nbx) * 128;

    const int rowL = lane >> 3;
    const int gS   = (lane & 7) ^ rowL;
    const int wr   = (w >> 1) * 32, wc = (w & 1) * 64;

    f32x4 acc[2][4] = {};

    auto stage = [&](int buf, int kb) {
        #pragma unroll
        for (int ci = 0; ci < 2; ci++) {
            const int chunk = w * 2 + ci;
            const int row   = chunk * 8 + rowL;
            const unsigned short* gpA = &A[(size_t)(m0 + row) * HID + kb + gS * 8];
            __builtin_amdgcn_global_load_lds(
                (const __attribute__((address_space(1))) void*)gpA,
                (__attribute__((address_space(3))) void*)(&AsBase[buf * 4096 + chunk * 512]),
                16, 0, 0);
        }
        #pragma unroll
        for (int ci = 0; ci < 4; ci++) {
            const int chunk = w * 4 + ci;
            const int row   = chunk * 8 + rowL;
            const unsigned short* gpB = &B[(size_t)(n0 + row) * HID + kb + gS * 8];
            __builtin_amdgcn_global_load_lds(
                (const __attribute__((address_space(1))) void*)gpB,
                (__attribute__((address_space(3))) void*)(&BsBase[buf * 8192 + chunk * 512]),
                16, 0, 0);
        }
    };

    stage(0, 0);
    const int nk = HID >> 6;
    for (int t = 0; t < nk; ++t) {
        if (t + 1 < nk) {
            stage((t + 1) & 1, (t + 1) * 64);
            asm volatile("s_waitcnt vmcnt(6)" ::: "memory");
        } else {
            asm volatile("s_waitcnt vmcnt(0)" ::: "memory");
        }
        __syncthreads();

        const unsigned short* As_ = &AsBase[(t & 1) * 4096];
        const unsigned short* Bs_ = &BsBase[(t & 1) * 8192];
        #pragma unroll
        for (int kk = 0; kk < 2; kk++) {
            u16x8 af[2], bf[4];
            const int g = (kk * 4 + lg) ^ (lc & 7);
            #pragma unroll
            for (int mi = 0; mi < 2; mi++) {
                const int r = wr + mi * 16 + lc;
                af[mi] = *reinterpret_cast<const u16x8*>(&As_[r * 64 + g * 8]);
            }
            #pragma unroll
            for (int ni = 0; ni < 4; ni++) {
                const int r = wc + ni * 16 + lc;
                bf[ni] = *reinterpret_cast<const u16x8*>(&Bs_[r * 64 + g * 8]);
            }
            #pragma unroll
            for (int mi = 0; mi < 2; mi++)
                #pragma unroll
                for (int ni = 0; ni < 4; ni++)
                    acc[mi][ni] = mfma16(af[mi], bf[ni], acc[mi][ni]);
        }
        __syncthreads();
    }

    // ------------------ fused epilogue ------------------
    if (n0 < QDIM + KVDIM) {
        float* Ep = (float*)smem;                        // 64 x 132 f32
        #pragma unroll
        for (int mi = 0; mi < 2; mi++)
            #pragma unroll
            for (int ni = 0; ni < 4; ni++)
                #pragma unroll
                for (int j = 0; j < 4; j++)
                    Ep[(wr + mi * 16 + lg * 4 + j) * 132 + wc + ni * 16 + lc]
                        = acc[mi][ni][j];
        __syncthreads();

        const bool isq = (n0 < QDIM);
        const float scl = isq ? QSCL : 1.0f;
        unsigned short* dst  = isq ? qr : kr;
        const int rowstride  = isq ? QDIM : KVDIM;
        const int colbase    = isq ? n0 : (n0 - QDIM);

        const int r  = tid >> 2;
        const int jb = (tid & 3) * 16;
        const float* ct = ctab + (size_t)(m0 + r) * 128;
        unsigned short* drow = dst + (size_t)(m0 + r) * rowstride + colbase;
        #pragma unroll
        for (int g = 0; g < 4; g++) {
            ushort4 p1, p2;
            #pragma unroll
            for (int e = 0; e < 4; e++) {
                const int j = jb + g * 4 + e;
                float x1 = Ep[r * 132 + j];
                float x2 = Ep[r * 132 + j + 64];
                float c = ct[j], s = ct[64 + j];
                ((unsigned short*)&p1)[e] = f2bf((x1 * c - x2 * s) * scl);
                ((unsigned short*)&p2)[e] = f2bf((x2 * c + x1 * s) * scl);
            }
            *reinterpret_cast<ushort4*>(drow + jb + g * 4)      = p1;
            *reinterpret_cast<ushort4*>(drow + jb + g * 4 + 64) = p2;
        }
    } else {
        #pragma unroll
        for (int mi = 0; mi < 2; mi++)
            #pragma unroll
            for (int ni = 0; ni < 4; ni++) {
                const int d   = (n0 - QDIM - KVDIM) + wc + ni * 16 + lc;
                const int t0r = m0 + wr + mi * 16 + lg * 4;
                ushort4 pk;
                pk.x = f2bf(acc[mi][ni][0]);
                pk.y = f2bf(acc[mi][ni][1]);
                pk.z = f2bf(acc[mi][ni][2]);
                pk.w = f2bf(acc[mi][ni][3]);
                *reinterpret_cast<ushort4*>(&vt[(size_t)d * T_TOK + t0r]) = pk;
            }
    }
}

// ---------------------------------------------------------------------------
// K1b: generic bf16 GEMM (out-proj). 64x128 tile, BK=64, dbuf
// global_load_lds + counted vmcnt(6), XCD swizzle.
// ---------------------------------------------------------------------------
__global__ __launch_bounds__(256) void gemm_out(
    const unsigned short* __restrict__ A,   // att bf16 [T][QDIM]
    const unsigned short* __restrict__ B,   // Wob bf16 [HID][QDIM]
    float* __restrict__ C)                  // fp32 [T][HID]
{
    __shared__ alignas(16) unsigned short As[2][64 * 64];
    __shared__ alignas(16) unsigned short Bs[2][128 * 64];

    const int tid  = threadIdx.x;
    const int lane = tid & 63;
    const int w    = tid >> 6;
    const int lg   = lane >> 4, lc = lane & 15;

    const int nbx = HID / 128;               // 16
    const int cpx = gridDim.x >> 3;
    const int wg  = (blockIdx.x & 7) * cpx + (blockIdx.x >> 3);
    const int m0  = (wg / nbx) * 64, n0 = (wg % nbx) * 128;

    const int rowL = lane >> 3;
    const int gS   = (lane & 7) ^ rowL;
    const int wr   = (w >> 1) * 32, wc = (w & 1) * 64;

    f32x4 acc[2][4] = {};

    auto stage = [&](int buf, int kb) {
        #pragma unroll
        for (int ci = 0; ci < 2; ci++) {
            const int chunk = w * 2 + ci;
            const int row   = chunk * 8 + rowL;
            const unsigned short* gpA = &A[(size_t)(m0 + row) * QDIM + kb + gS * 8];
            __builtin_amdgcn_global_load_lds(
                (const __attribute__((address_space(1))) void*)gpA,
                (__attribute__((address_space(3))) void*)(&As[buf][chunk * 512]),
                16, 0, 0);
        }
        #pragma unroll
        for (int ci = 0; ci < 4; ci++) {
            const int chunk = w * 4 + ci;
            const int row   = chunk * 8 + rowL;
            const unsigned short* gpB = &B[(size_t)(n0 + row) * QDIM + kb + gS * 8];
            __builtin_amdgcn_global_load_lds(
                (const __attribute__((address_space(1))) void*)gpB,
                (__attribute__((address_space(3))) void*)(&Bs[buf][chunk * 512]),
                16, 0, 0);
        }
    };

    stage(0, 0);
    const int nk = QDIM >> 6;
    for (int t = 0; t < nk; ++t) {
        if (t + 1 < nk) {
            stage((t + 1) & 1, (t + 1) * 64);
            asm volatile("s_waitcnt vmcnt(6)" ::: "memory");
        } else {
            asm volatile("s_waitcnt vmcnt(0)" ::: "memory");
        }
        __syncthreads();

        const unsigned short* As_ = As[t & 1];
        const unsigned short* Bs_ = Bs[t & 1];
        #pragma unroll
        for (int kk = 0; kk < 2; kk++) {
            u16x8 af[2], bf[4];
            const int g = (kk * 4 + lg) ^ (lc & 7);
            #pragma unroll
            for (int mi = 0; mi < 2; mi++) {
                const int r = wr + mi * 16 + lc;
                af[mi] = *reinterpret_cast<const u16x8*>(&As_[r * 64 + g * 8]);
            }
            #pragma unroll
            for (int ni = 0; ni < 4; ni++) {
                const int r = wc + ni * 16 + lc;
                bf[ni] = *reinterpret_cast<const u16x8*>(&Bs_[r * 64 + g * 8]);
            }
            #pragma unroll
            for (int mi = 0; mi < 2; mi++)
                #pragma unroll
                for (int ni = 0; ni < 4; ni++)
                    acc[mi][ni] = mfma16(af[mi], bf[ni], acc[mi][ni]);
        }
        __syncthreads();
    }

    #pragma unroll
    for (int mi = 0; mi < 2; mi++)
        #pragma unroll
        for (int ni = 0; ni < 4; ni++)
            #pragma unroll
            for (int j = 0; j < 4; j++)
                C[(size_t)(m0 + wr + mi * 16 + lg * 4 + j) * HID
                  + n0 + wc + ni * 16 + lc] = acc[mi][ni][j];
}

// ---------------------------------------------------------------------------
// K3: causal GQA flash attention. Table-scheduled split-K (max chunk 11,
// 1008 blocks, LPT). Single-buffered K/V via global_load_lds; P-buffer
// XOR-swizzled [4][16][64] (no pad) -> LDS 40960 B = 4 blocks/CU.
// ---------------------------------------------------------------------------
__global__ __launch_bounds__(256) void attn_kernel(
    const unsigned short* __restrict__ q,   // bf16, pre-scaled by QSCL
    const unsigned short* __restrict__ k,
    const unsigned short* __restrict__ vt,  // bf16 [KVDIM][T]
    unsigned short* __restrict__ o,
    char* __restrict__ wsb)
{
    __shared__ alignas(16) unsigned short Ks[64 * 128];
    __shared__ alignas(16) unsigned short Vs[128 * 64];
    __shared__ alignas(16) unsigned short P[4][16][64];   // XOR-swizzled

    const int tid  = threadIdx.x;
    const int lane = tid & 63;
    const int w    = tid >> 6;
    const int lg   = lane >> 4, lc = lane & 15;
    const int b    = blockIdx.x;
    const int h    = b & 15;
    const int e    = b >> 4;                 // 0..62 schedule entry

    const int tau    = S_TAU[e];
    const int kstart = S_CST[e];             // in 64-key blocks
    const int kcnt   = S_CNT[e];
    const int slt    = S_SLT[e];             // 255 = direct write

    const int q0   = tau * 64 + w * 16;
    const int hk   = h >> 3;
    const int xr   = (lc & 7) << 4;

    const int krow_l = (lane >> 4);
    const int kgS    = (lane & 15);
    const int vrow_l = (lane >> 3);
    const int vgS    = (lane & 7);

    u16x8 qf[4];
    #pragma unroll
    for (int dc = 0; dc < 4; dc++)
        qf[dc] = *reinterpret_cast<const u16x8*>(
            &q[(size_t)(q0 + lc) * QDIM + h * HD + dc * 32 + lg * 8]);

    float mrow = -1e30f, ell = 0.f;          // log2 units
    f32x4 oacc[8] = {};

    char* Pw = (char*)P + w * 2048 + lc * 128;

    auto stage = [&](int kb) {
        #pragma unroll
        for (int ci = 0; ci < 4; ci++) {     // K first (vmcnt FIFO)
            const int chunk = w * 4 + ci;
            const int row   = chunk * 4 + krow_l;
            const int gSk   = kgS ^ (row & 7);
            const unsigned short* gp =
                &k[(size_t)(kb + row) * KVDIM + hk * HD + gSk * 8];
            __builtin_amdgcn_global_load_lds(
                (const __attribute__((address_space(1))) void*)gp,
                (__attribute__((address_space(3))) void*)(&Ks[chunk * 512]),
                16, 0, 0);
        }
        #pragma unroll
        for (int ci = 0; ci < 4; ci++) {     // then V
            const int chunk = w * 4 + ci;
            const int dr    = chunk * 8 + vrow_l;
            const int gSv   = vgS ^ (dr & 7);
            const unsigned short* gp =
                &vt[(size_t)(hk * HD + dr) * T_TOK + kb + gSv * 8];
            __builtin_amdgcn_global_load_lds(
                (const __attribute__((address_space(1))) void*)gp,
                (__attribute__((address_space(3))) void*)(&Vs[chunk * 512]),
                16, 0, 0);
        }
    };

    for (int it = 0; it < kcnt; ++it) {
        const int kb = (kstart + it) * 64;
        stage(kb);
        asm volatile("s_waitcnt vmcnt(4)" ::: "memory");   // K landed (this wave)
        __syncthreads();                                   // K landed (all waves)

        const char* KsB = (const char*)Ks;
        const char* VsB = (const char*)Vs;

        float sc[4][4];
        const bool dia = (kb + 63 > q0);
        #pragma unroll
        for (int c4 = 0; c4 < 4; c4++) {
            const int row = c4 * 16 + lc;
            f32x4 s = {0.f, 0.f, 0.f, 0.f};
            #pragma unroll
            for (int dc = 0; dc < 4; dc++) {
                u16x8 kf = *reinterpret_cast<const u16x8*>(
                    KsB + row * 256 + ((dc * 64 + lg * 16) ^ xr));
                s = mfma16(kf, qf[dc], s);   // SWAPPED: A=K, B=Q
            }
            if (dia) {
                #pragma unroll
                for (int j = 0; j < 4; j++) {
                    const int kpos = kb + c4 * 16 + lg * 4 + j;
                    sc[c4][j] = (kpos <= q0 + lc) ? s[j] : -1e30f;
                }
            } else {
                #pragma unroll
                for (int j = 0; j < 4; j++) sc[c4][j] = s[j];
            }
        }

        float t01 = fmaxf(fmaxf(sc[0][0], sc[0][1]), fmaxf(sc[0][2], sc[0][3]));
        float t23 = fmaxf(fmaxf(sc[1][0], sc[1][1]), fmaxf(sc[1][2], sc[1][3]));
        float t45 = fmaxf(fmaxf(sc[2][0], sc[2][1]), fmaxf(sc[2][2], sc[2][3]));
        float t67 = fmaxf(fmaxf(sc[3][0], sc[3][1]), fmaxf(sc[3][2], sc[3][3]));
        float tmx = fmaxf(fmaxf(t01, t23), fmaxf(t45, t67));
        tmx = fmaxf(tmx, __shfl_xor(tmx, 16));
        tmx = fmaxf(tmx, __shfl_xor(tmx, 32));

        float mn;
        if (__all(tmx <= mrow + DEFER_THR)) {   // defer-max (T13)
            mn = mrow;
        } else {
            mn = fmaxf(mrow, tmx);
            float alpha = __builtin_amdgcn_exp2f(mrow - mn);
            mrow = mn;
            ell *= alpha;
            float aj[4];
            #pragma unroll
            for (int j = 0; j < 4; j++)
                aj[j] = __shfl(alpha, lg * 4 + j);
            #pragma unroll
            for (int d8 = 0; d8 < 8; d8++)
                #pragma unroll
                for (int j = 0; j < 4; j++)
                    oacc[d8][j] *= aj[j];
        }

        float rs = 0.f;
        #pragma unroll
        for (int c4 = 0; c4 < 4; c4++) {
            float p0 = __builtin_amdgcn_exp2f(sc[c4][0] - mn);
            float p1 = __builtin_amdgcn_exp2f(sc[c4][1] - mn);
            float p2 = __builtin_amdgcn_exp2f(sc[c4][2] - mn);
            float p3 = __builtin_amdgcn_exp2f(sc[c4][3] - mn);
            rs += (p0 + p1) + (p2 + p3);
            ushort4 pk;
            pk.x = f2bf(p0); pk.y = f2bf(p1); pk.z = f2bf(p2); pk.w = f2bf(p3);
            // swizzled P write: element k -> byte (k*2)^xr within row
            *reinterpret_cast<ushort4*>(Pw + ((c4 * 32 + lg * 8) ^ xr)) = pk;
        }
        rs += __shfl_xor(rs, 16);
        rs += __shfl_xor(rs, 32);
        ell += rs;

        // V landed on all waves before PV reads Vs
        asm volatile("s_waitcnt vmcnt(0) lgkmcnt(0)" ::: "memory");
        __builtin_amdgcn_sched_barrier(0);
        __syncthreads();

        u16x8 pf0 = *reinterpret_cast<const u16x8*>(Pw + ((lg * 16) ^ xr));
        u16x8 pf1 = *reinterpret_cast<const u16x8*>(Pw + ((64 + lg * 16) ^ xr));

        #pragma unroll
        for (int d8 = 0; d8 < 8; d8++) {
            const int drow = d8 * 16 + lc;
            u16x8 vf0 = *reinterpret_cast<const u16x8*>(
                VsB + drow * 128 + ((lg * 16) ^ xr));
            u16x8 vf1 = *reinterpret_cast<const u16x8*>(
                VsB + drow * 128 + ((lg * 16 + 64) ^ xr));
            oacc[d8] = mfma16(pf0, vf0, oacc[d8]);
            oacc[d8] = mfma16(pf1, vf1, oacc[d8]);
        }
        if (it + 1 < kcnt) __syncthreads();   // done reading Ks/Vs before restage
    }

    if (slt == 255) {
        float ej[4];
        #pragma unroll
        for (int j = 0; j < 4; j++)
            ej[j] = __shfl(ell, lg * 4 + j);
        #pragma unroll
        for (int d8 = 0; d8 < 8; d8++)
            #pragma unroll
            for (int j = 0; j < 4; j++) {
                float val = oacc[d8][j] / ej[j];
                o[(size_t)(q0 + lg * 4 + j) * QDIM + h * HD + d8 * 16 + lc] = f2bf(val);
            }
    } else {
        const int slot = h * 52 + slt;
        float* po = slotO(wsb, slot);
        float* pML = (float*)(wsb + PML_OFF);
        #pragma unroll
        for (int d8 = 0; d8 < 8; d8++)
            #pragma unroll
            for (int j = 0; j < 4; j++)
                po[(w * 16 + lg * 4 + j) * 128 + d8 * 16 + lc] = oacc[d8][j];
        if (lg == 0) {
            pML[slot * 128 + w * 16 + lc]      = mrow;
            pML[slot * 128 + 64 + w * 16 + lc] = ell;
        }
    }
}

// ---------------------------------------------------------------------------
// K3b: combine 2..3 split-K partials -> bf16 output. Grid (21, 16);
// tau = 11 + bx; nch block-uniform (rule #20 safe).
// ---------------------------------------------------------------------------
__global__ __launch_bounds__(256) void attn_combine(
    char* __restrict__ wsb,
    unsigned short* __restrict__ o)
{
    const int tau = 11 + blockIdx.x;         // 11..31
    const int h   = blockIdx.y;
    const int nch = (tau <= 21) ? 2 : 3;
    const int sb  = h * 52 + (tau <= 21 ? (tau - 11) * 2 : 22 + (tau - 22) * 3);
    const float* pML = (const float*)(wsb + PML_OFF);

    const int tid = threadIdx.x;
    const int r   = tid >> 2;
    const int cg  = (tid & 3) * 32;

    float m0v = pML[(sb + 0) * 128 + r], l0v = pML[(sb + 0) * 128 + 64 + r];
    float m1v = pML[(sb + 1) * 128 + r], l1v = pML[(sb + 1) * 128 + 64 + r];
    float m2v = -1e30f, l2v = 0.f;
    if (nch > 2) { m2v = pML[(sb + 2) * 128 + r]; l2v = pML[(sb + 2) * 128 + 64 + r]; }

    const float M  = fmaxf(fmaxf(m0v, m1v), m2v);
    const float w0 = __builtin_amdgcn_exp2f(m0v - M);
    const float w1 = __builtin_amdgcn_exp2f(m1v - M);
    const float w2 = nch > 2 ? __builtin_amdgcn_exp2f(m2v - M) : 0.f;
    const float rn = 1.0f / (w0 * l0v + w1 * l1v + w2 * l2v);

    const float* o0 = slotO(wsb, sb + 0) + r * 128 + cg;
    const float* o1 = slotO(wsb, sb + 1) + r * 128 + cg;
    const float* o2 = slotO(wsb, sb + 2) + r * 128 + cg;
    unsigned short* dst = o + (size_t)(tau * 64 + r) * QDIM + h * HD + cg;

    #pragma unroll
    for (int g = 0; g < 8; g++) {
        float4 a0 = *reinterpret_cast<const float4*>(o0 + g * 4);
        float4 a1 = *reinterpret_cast<const float4*>(o1 + g * 4);
        float ax = w0 * a0.x + w1 * a1.x;
        float ay = w0 * a0.y + w1 * a1.y;
        float az = w0 * a0.z + w1 * a1.z;
        float aw = w0 * a0.w + w1 * a1.w;
        if (nch > 2) {
            float4 a2 = *reinterpret_cast<const float4*>(o2 + g * 4);
            ax += w2 * a2.x; ay += w2 * a2.y; az += w2 * a2.z; aw += w2 * a2.w;
        }
        ushort4 pk;
        pk.x = f2bf(ax * rn); pk.y = f2bf(ay * rn);
        pk.z = f2bf(az * rn); pk.w = f2bf(aw * rn);
        *reinterpret_cast<ushort4*>(dst + g * 4) = pk;
    }
}

// ---------------------------------------------------------------------------
extern "C" void kernel_launch(void* const* d_in, const int* in_sizes, int n_in,
                              void* d_out, int out_size, void* d_ws, size_t ws_size,
                              hipStream_t stream) {
    const float* hidden    = (const float*)d_in[0];
    const int*   positions = (const int*)d_in[1];
    const float* Wq        = (const float*)d_in[2];
    const float* Wk        = (const float*)d_in[3];
    const float* Wv        = (const float*)d_in[4];
    const float* Wo        = (const float*)d_in[5];
    float*       out       = (float*)d_out;

    char* ws = (char*)d_ws;
    unsigned short* hb   = (unsigned short*)(ws);           // [0, 8388608)
    unsigned short* Wf   = (unsigned short*)(ws + 8388608); // [8388608, 18874368)
    float*          ctab = (float*)(ws + 18874368);         // [18874368, 19922944)
    unsigned short* qr   = (unsigned short*)(ws + 19922944);
    unsigned short* kr   = (unsigned short*)(ws + 28311552);
    unsigned short* vt   = (unsigned short*)(ws + 29360128);
    unsigned short* att  = (unsigned short*)(ws + 30408704);
    unsigned short* Wob  = (unsigned short*)(ws + 38797312);
    // pO slots 0-575 at [47185920, 66060288); 576-831 alias hb; pML at 66060288

    pack_bf16_all<<<7168, 256, 0, stream>>>(hidden, Wq, Wk, Wv, Wo, positions,
                                            hb, Wf, Wob, ctab);
    qkv_gemm_fused<<<640, 256, 0, stream>>>(hb, Wf, ctab, qr, kr, vt);
    attn_kernel<<<NH * 63, 256, 0, stream>>>(qr, kr, vt, att, ws);
    attn_combine<<<dim3(21, 16), 256, 0, stream>>>(ws, att);
    gemm_out<<<512, 256, 0, stream>>>(att, Wob, out);
}

// Round 14
// 127.246 us; speedup vs baseline: 1.1166x; 1.1166x over previous
//
#include <hip/hip_runtime.h>

#define T_TOK 2048
#define HID   2048
#define NH    16
#define NKV   2
#define HD    128
#define QDIM  (NH * HD)                 // 2048
#define KVDIM (NKV * HD)                // 256
#define QKVDIM (QDIM + 2 * KVDIM)       // 2560

typedef float          f32x4  __attribute__((ext_vector_type(4)));
typedef unsigned short u16x8  __attribute__((ext_vector_type(8)));
typedef __bf16         bf16x8 __attribute__((ext_vector_type(8)));

__device__ __forceinline__ unsigned short f2bf(float f) {
    __bf16 h = (__bf16)f;
    return __builtin_bit_cast(unsigned short, h);
}

__device__ __forceinline__ f32x4 mfma16(u16x8 a, u16x8 b, f32x4 c) {
    return __builtin_amdgcn_mfma_f32_16x16x32_bf16(
        __builtin_bit_cast(bf16x8, a), __builtin_bit_cast(bf16x8, b), c, 0, 0, 0);
}

#define QSCL 0.12751743f        // 128^-0.5 * log2(e)
#define DEFER_THR 11.5416f      // defer-max threshold (log2 units)

// ---------------------------------------------------------------------------
// K0: fp32->bf16 packs (blocks 0..6655) + RoPE cos/sin table (6656..7167).
// ---------------------------------------------------------------------------
__global__ __launch_bounds__(256) void pack_bf16_all(
    const float* __restrict__ hidden, const float* __restrict__ Wq,
    const float* __restrict__ Wk, const float* __restrict__ Wv,
    const float* __restrict__ Wo, const int* __restrict__ positions,
    unsigned short* __restrict__ hb, unsigned short* __restrict__ Wf,
    unsigned short* __restrict__ Wob, float* __restrict__ ctab)
{
    const int b = blockIdx.x;
    if (b >= 6656) {
        const int bb = b - 6656;                 // 0..511
        const int t  = bb * 4 + (threadIdx.x >> 6);
        const int j  = threadIdx.x & 63;
        float invf = expf(-(float)j * 0.14391156831212787f);  // 10000^(-j/64)
        float f = (float)positions[t] * invf;
        ctab[(size_t)t * 128 + j]      = cosf(f);
        ctab[(size_t)t * 128 + 64 + j] = sinf(f);
        return;
    }
    const float* src; unsigned short* dst; size_t off;
    if      (b < 2048) { src = hidden; dst = hb;            off = (size_t)b * 2048; }
    else if (b < 4096) { src = Wq;     dst = Wf;            off = (size_t)(b - 2048) * 2048; }
    else if (b < 4352) { src = Wk;     dst = Wf + 4194304;  off = (size_t)(b - 4096) * 2048; }
    else if (b < 4608) { src = Wv;     dst = Wf + 4718592;  off = (size_t)(b - 4352) * 2048; }
    else               { src = Wo;     dst = Wob;           off = (size_t)(b - 4608) * 2048; }

    const size_t i = off + threadIdx.x * 8;
    float4 f0 = *reinterpret_cast<const float4*>(src + i);
    float4 f1 = *reinterpret_cast<const float4*>(src + i + 4);
    u16x8 o;
    o[0]=f2bf(f0.x); o[1]=f2bf(f0.y); o[2]=f2bf(f0.z); o[3]=f2bf(f0.w);
    o[4]=f2bf(f1.x); o[5]=f2bf(f1.y); o[6]=f2bf(f1.z); o[7]=f2bf(f1.w);
    *reinterpret_cast<u16x8*>(dst + i) = o;
}

// ---------------------------------------------------------------------------
// K1a: fused QKV GEMM. 64x128 tile, BK=64, dbuf global_load_lds + counted
// vmcnt(6), XCD swizzle. Epilogue fuses RoPE (q pre-scaled by QSCL) and
// V-transpose. (round-12 verbatim)
// ---------------------------------------------------------------------------
__global__ __launch_bounds__(256) void qkv_gemm_fused(
    const unsigned short* __restrict__ A,   // hb  bf16 [2048][2048]
    const unsigned short* __restrict__ B,   // Wf  bf16 [2560][2048]
    const float* __restrict__ ctab,         // [T][128] cos|sin
    unsigned short* __restrict__ qr,        // bf16 [T][QDIM], pre-scaled
    unsigned short* __restrict__ kr,        // bf16 [T][KVDIM]
    unsigned short* __restrict__ vt)        // bf16 [KVDIM][T]
{
    __shared__ alignas(16) char smem[49152];
    unsigned short* AsBase = (unsigned short*)smem;           // [2][4096]
    unsigned short* BsBase = (unsigned short*)(smem + 16384); // [2][8192]

    const int tid  = threadIdx.x;
    const int lane = tid & 63;
    const int w    = tid >> 6;
    const int lg   = lane >> 4, lc = lane & 15;

    const int nbx = QKVDIM / 128;            // 20
    const int cpx = gridDim.x >> 3;
    const int wg  = (blockIdx.x & 7) * cpx + (blockIdx.x >> 3);
    const int m0  = (wg / nbx) * 64, n0 = (wg % nbx) * 128;

    const int rowL = lane >> 3;
    const int gS   = (lane & 7) ^ rowL;
    const int wr   = (w >> 1) * 32, wc = (w & 1) * 64;

    f32x4 acc[2][4] = {};

    auto stage = [&](int buf, int kb) {
        #pragma unroll
        for (int ci = 0; ci < 2; ci++) {
            const int chunk = w * 2 + ci;
            const int row   = chunk * 8 + rowL;
            const unsigned short* gpA = &A[(size_t)(m0 + row) * HID + kb + gS * 8];
            __builtin_amdgcn_global_load_lds(
                (const __attribute__((address_space(1))) void*)gpA,
                (__attribute__((address_space(3))) void*)(&AsBase[buf * 4096 + chunk * 512]),
                16, 0, 0);
        }
        #pragma unroll
        for (int ci = 0; ci < 4; ci++) {
            const int chunk = w * 4 + ci;
            const int row   = chunk * 8 + rowL;
            const unsigned short* gpB = &B[(size_t)(n0 + row) * HID + kb + gS * 8];
            __builtin_amdgcn_global_load_lds(
                (const __attribute__((address_space(1))) void*)gpB,
                (__attribute__((address_space(3))) void*)(&BsBase[buf * 8192 + chunk * 512]),
                16, 0, 0);
        }
    };

    stage(0, 0);
    const int nk = HID >> 6;
    for (int t = 0; t < nk; ++t) {
        if (t + 1 < nk) {
            stage((t + 1) & 1, (t + 1) * 64);
            asm volatile("s_waitcnt vmcnt(6)" ::: "memory");
        } else {
            asm volatile("s_waitcnt vmcnt(0)" ::: "memory");
        }
        __syncthreads();

        const unsigned short* As_ = &AsBase[(t & 1) * 4096];
        const unsigned short* Bs_ = &BsBase[(t & 1) * 8192];
        #pragma unroll
        for (int kk = 0; kk < 2; kk++) {
            u16x8 af[2], bf[4];
            const int g = (kk * 4 + lg) ^ (lc & 7);
            #pragma unroll
            for (int mi = 0; mi < 2; mi++) {
                const int r = wr + mi * 16 + lc;
                af[mi] = *reinterpret_cast<const u16x8*>(&As_[r * 64 + g * 8]);
            }
            #pragma unroll
            for (int ni = 0; ni < 4; ni++) {
                const int r = wc + ni * 16 + lc;
                bf[ni] = *reinterpret_cast<const u16x8*>(&Bs_[r * 64 + g * 8]);
            }
            #pragma unroll
            for (int mi = 0; mi < 2; mi++)
                #pragma unroll
                for (int ni = 0; ni < 4; ni++)
                    acc[mi][ni] = mfma16(af[mi], bf[ni], acc[mi][ni]);
        }
        __syncthreads();
    }

    // ------------------ fused epilogue ------------------
    if (n0 < QDIM + KVDIM) {
        float* Ep = (float*)smem;                        // 64 x 132 f32
        #pragma unroll
        for (int mi = 0; mi < 2; mi++)
            #pragma unroll
            for (int ni = 0; ni < 4; ni++)
                #pragma unroll
                for (int j = 0; j < 4; j++)
                    Ep[(wr + mi * 16 + lg * 4 + j) * 132 + wc + ni * 16 + lc]
                        = acc[mi][ni][j];
        __syncthreads();

        const bool isq = (n0 < QDIM);
        const float scl = isq ? QSCL : 1.0f;
        unsigned short* dst  = isq ? qr : kr;
        const int rowstride  = isq ? QDIM : KVDIM;
        const int colbase    = isq ? n0 : (n0 - QDIM);

        const int r  = tid >> 2;
        const int jb = (tid & 3) * 16;
        const float* ct = ctab + (size_t)(m0 + r) * 128;
        unsigned short* drow = dst + (size_t)(m0 + r) * rowstride + colbase;
        #pragma unroll
        for (int g = 0; g < 4; g++) {
            ushort4 p1, p2;
            #pragma unroll
            for (int e = 0; e < 4; e++) {
                const int j = jb + g * 4 + e;
                float x1 = Ep[r * 132 + j];
                float x2 = Ep[r * 132 + j + 64];
                float c = ct[j], s = ct[64 + j];
                ((unsigned short*)&p1)[e] = f2bf((x1 * c - x2 * s) * scl);
                ((unsigned short*)&p2)[e] = f2bf((x2 * c + x1 * s) * scl);
            }
            *reinterpret_cast<ushort4*>(drow + jb + g * 4)      = p1;
            *reinterpret_cast<ushort4*>(drow + jb + g * 4 + 64) = p2;
        }
    } else {
        #pragma unroll
        for (int mi = 0; mi < 2; mi++)
            #pragma unroll
            for (int ni = 0; ni < 4; ni++) {
                const int d   = (n0 - QDIM - KVDIM) + wc + ni * 16 + lc;
                const int t0r = m0 + wr + mi * 16 + lg * 4;
                ushort4 pk;
                pk.x = f2bf(acc[mi][ni][0]);
                pk.y = f2bf(acc[mi][ni][1]);
                pk.z = f2bf(acc[mi][ni][2]);
                pk.w = f2bf(acc[mi][ni][3]);
                *reinterpret_cast<ushort4*>(&vt[(size_t)d * T_TOK + t0r]) = pk;
            }
    }
}

// ---------------------------------------------------------------------------
// K1b: out-proj GEMM. 64x128 tile, BK=64, THREE-DEEP pipelined
// global_load_lds (issue stage(t+2), wait vmcnt(12): two compute phases of
// latency cover). LDS 72 KB -> 2 blocks/CU = its grid density (512 = 2/CU).
// ---------------------------------------------------------------------------
__global__ __launch_bounds__(256) void gemm_out(
    const unsigned short* __restrict__ A,   // att bf16 [T][QDIM]
    const unsigned short* __restrict__ B,   // Wob bf16 [HID][QDIM]
    float* __restrict__ C)                  // fp32 [T][HID]
{
    __shared__ alignas(16) unsigned short As[3][64 * 64];
    __shared__ alignas(16) unsigned short Bs[3][128 * 64];

    const int tid  = threadIdx.x;
    const int lane = tid & 63;
    const int w    = tid >> 6;
    const int lg   = lane >> 4, lc = lane & 15;

    const int nbx = HID / 128;               // 16
    const int cpx = gridDim.x >> 3;
    const int wg  = (blockIdx.x & 7) * cpx + (blockIdx.x >> 3);
    const int m0  = (wg / nbx) * 64, n0 = (wg % nbx) * 128;

    const int rowL = lane >> 3;
    const int gS   = (lane & 7) ^ rowL;
    const int wr   = (w >> 1) * 32, wc = (w & 1) * 64;

    f32x4 acc[2][4] = {};

    auto stage = [&](int buf, int kb) {
        #pragma unroll
        for (int ci = 0; ci < 2; ci++) {
            const int chunk = w * 2 + ci;
            const int row   = chunk * 8 + rowL;
            const unsigned short* gpA = &A[(size_t)(m0 + row) * QDIM + kb + gS * 8];
            __builtin_amdgcn_global_load_lds(
                (const __attribute__((address_space(1))) void*)gpA,
                (__attribute__((address_space(3))) void*)(&As[buf][chunk * 512]),
                16, 0, 0);
        }
        #pragma unroll
        for (int ci = 0; ci < 4; ci++) {
            const int chunk = w * 4 + ci;
            const int row   = chunk * 8 + rowL;
            const unsigned short* gpB = &B[(size_t)(n0 + row) * QDIM + kb + gS * 8];
            __builtin_amdgcn_global_load_lds(
                (const __attribute__((address_space(1))) void*)gpB,
                (__attribute__((address_space(3))) void*)(&Bs[buf][chunk * 512]),
                16, 0, 0);
        }
    };

    stage(0, 0);
    stage(1, 64);
    const int nk = QDIM >> 6;                // 32
    int buf = 0;
    for (int t = 0; t < nk; ++t) {
        if (t + 2 < nk) {
            stage((t + 2) % 3, (t + 2) * 64);           // keep pipe 3-deep
            asm volatile("s_waitcnt vmcnt(12)" ::: "memory");  // stage(t) landed
        } else if (t + 1 < nk) {
            asm volatile("s_waitcnt vmcnt(6)" ::: "memory");
        } else {
            asm volatile("s_waitcnt vmcnt(0)" ::: "memory");
        }
        __syncthreads();

        const unsigned short* As_ = As[buf];
        const unsigned short* Bs_ = Bs[buf];
        #pragma unroll
        for (int kk = 0; kk < 2; kk++) {
            u16x8 af[2], bf[4];
            const int g = (kk * 4 + lg) ^ (lc & 7);
            #pragma unroll
            for (int mi = 0; mi < 2; mi++) {
                const int r = wr + mi * 16 + lc;
                af[mi] = *reinterpret_cast<const u16x8*>(&As_[r * 64 + g * 8]);
            }
            #pragma unroll
            for (int ni = 0; ni < 4; ni++) {
                const int r = wc + ni * 16 + lc;
                bf[ni] = *reinterpret_cast<const u16x8*>(&Bs_[r * 64 + g * 8]);
            }
            #pragma unroll
            for (int mi = 0; mi < 2; mi++)
                #pragma unroll
                for (int ni = 0; ni < 4; ni++)
                    acc[mi][ni] = mfma16(af[mi], bf[ni], acc[mi][ni]);
        }
        __syncthreads();
        buf = (buf == 2) ? 0 : buf + 1;
    }

    #pragma unroll
    for (int mi = 0; mi < 2; mi++)
        #pragma unroll
        for (int ni = 0; ni < 4; ni++)
            #pragma unroll
            for (int j = 0; j < 4; j++)
                C[(size_t)(m0 + wr + mi * 16 + lg * 4 + j) * HID
                  + n0 + wc + ni * 16 + lc] = acc[mi][ni][j];
}

// ---------------------------------------------------------------------------
// K3: causal GQA flash attention (round-12 verbatim). Split-K <=16 k-blocks
// (768 blocks, LPT), single-buffered K/V via global_load_lds; vmcnt(4)
// before QK, vmcnt(0)+barrier before PV. P padded [72]; LDS 41984.
// ---------------------------------------------------------------------------
__global__ __launch_bounds__(256) void attn_kernel(
    const unsigned short* __restrict__ q,   // bf16, pre-scaled by QSCL
    const unsigned short* __restrict__ k,
    const unsigned short* __restrict__ vt,  // bf16 [KVDIM][T]
    unsigned short* __restrict__ o,
    float* __restrict__ pO,                 // fp32 [512][64][128]
    float* __restrict__ pML)                // fp32 [512][2][64]
{
    __shared__ alignas(16) unsigned short Ks[64 * 128];
    __shared__ alignas(16) unsigned short Vs[128 * 64];
    __shared__ alignas(16) unsigned short P[4][16][72];

    const int tid  = threadIdx.x;
    const int lane = tid & 63;
    const int w    = tid >> 6;
    const int lg   = lane >> 4, lc = lane & 15;
    const int b    = blockIdx.x;
    const int h    = b & 15;
    const int idx  = b >> 4;                 // 0..47, LPT order

    int tau, c0;
    if (idx <= 16)      { tau = 15 + idx; c0 = 0; }
    else if (idx == 17) { tau = 31;       c0 = 1; }
    else {
        int j = idx - 18, kk = 15 - (j >> 1);
        if ((j & 1) == 0) { tau = kk - 1;  c0 = 0; }
        else              { tau = kk + 15; c0 = 1; }
    }
    const int kstart = c0 << 4;              // in 64-key blocks
    const int kcnt   = min(16, tau + 1 - kstart);

    const int q0   = tau * 64 + w * 16;
    const int hk   = h >> 3;
    const int xr   = (lc & 7) << 4;

    const int krow_l = (lane >> 4);
    const int kgS    = (lane & 15);
    const int vrow_l = (lane >> 3);
    const int vgS    = (lane & 7);

    u16x8 qf[4];
    #pragma unroll
    for (int dc = 0; dc < 4; dc++)
        qf[dc] = *reinterpret_cast<const u16x8*>(
            &q[(size_t)(q0 + lc) * QDIM + h * HD + dc * 32 + lg * 8]);

    float mrow = -1e30f, ell = 0.f;          // log2 units
    f32x4 oacc[8] = {};

    auto stage = [&](int kb) {
        #pragma unroll
        for (int ci = 0; ci < 4; ci++) {     // K first (vmcnt FIFO)
            const int chunk = w * 4 + ci;
            const int row   = chunk * 4 + krow_l;
            const int gSk   = kgS ^ (row & 7);
            const unsigned short* gp =
                &k[(size_t)(kb + row) * KVDIM + hk * HD + gSk * 8];
            __builtin_amdgcn_global_load_lds(
                (const __attribute__((address_space(1))) void*)gp,
                (__attribute__((address_space(3))) void*)(&Ks[chunk * 512]),
                16, 0, 0);
        }
        #pragma unroll
        for (int ci = 0; ci < 4; ci++) {     // then V
            const int chunk = w * 4 + ci;
            const int dr    = chunk * 8 + vrow_l;
            const int gSv   = vgS ^ (dr & 7);
            const unsigned short* gp =
                &vt[(size_t)(hk * HD + dr) * T_TOK + kb + gSv * 8];
            __builtin_amdgcn_global_load_lds(
                (const __attribute__((address_space(1))) void*)gp,
                (__attribute__((address_space(3))) void*)(&Vs[chunk * 512]),
                16, 0, 0);
        }
    };

    for (int it = 0; it < kcnt; ++it) {
        const int kb = (kstart + it) * 64;
        stage(kb);
        asm volatile("s_waitcnt vmcnt(4)" ::: "memory");   // K landed (this wave)
        __syncthreads();                                   // K landed (all waves)

        const char* KsB = (const char*)Ks;
        const char* VsB = (const char*)Vs;

        float sc[4][4];
        const bool dia = (kb + 63 > q0);
        #pragma unroll
        for (int c4 = 0; c4 < 4; c4++) {
            const int row = c4 * 16 + lc;
            f32x4 s = {0.f, 0.f, 0.f, 0.f};
            #pragma unroll
            for (int dc = 0; dc < 4; dc++) {
                u16x8 kf = *reinterpret_cast<const u16x8*>(
                    KsB + row * 256 + ((dc * 64 + lg * 16) ^ xr));
                s = mfma16(kf, qf[dc], s);   // SWAPPED: A=K, B=Q
            }
            if (dia) {
                #pragma unroll
                for (int j = 0; j < 4; j++) {
                    const int kpos = kb + c4 * 16 + lg * 4 + j;
                    sc[c4][j] = (kpos <= q0 + lc) ? s[j] : -1e30f;
                }
            } else {
                #pragma unroll
                for (int j = 0; j < 4; j++) sc[c4][j] = s[j];
            }
        }

        float t01 = fmaxf(fmaxf(sc[0][0], sc[0][1]), fmaxf(sc[0][2], sc[0][3]));
        float t23 = fmaxf(fmaxf(sc[1][0], sc[1][1]), fmaxf(sc[1][2], sc[1][3]));
        float t45 = fmaxf(fmaxf(sc[2][0], sc[2][1]), fmaxf(sc[2][2], sc[2][3]));
        float t67 = fmaxf(fmaxf(sc[3][0], sc[3][1]), fmaxf(sc[3][2], sc[3][3]));
        float tmx = fmaxf(fmaxf(t01, t23), fmaxf(t45, t67));
        tmx = fmaxf(tmx, __shfl_xor(tmx, 16));
        tmx = fmaxf(tmx, __shfl_xor(tmx, 32));

        float mn;
        if (__all(tmx <= mrow + DEFER_THR)) {   // defer-max (T13)
            mn = mrow;
        } else {
            mn = fmaxf(mrow, tmx);
            float alpha = __builtin_amdgcn_exp2f(mrow - mn);
            mrow = mn;
            ell *= alpha;
            float aj[4];
            #pragma unroll
            for (int j = 0; j < 4; j++)
                aj[j] = __shfl(alpha, lg * 4 + j);
            #pragma unroll
            for (int d8 = 0; d8 < 8; d8++)
                #pragma unroll
                for (int j = 0; j < 4; j++)
                    oacc[d8][j] *= aj[j];
        }

        float rs = 0.f;
        #pragma unroll
        for (int c4 = 0; c4 < 4; c4++) {
            float p0 = __builtin_amdgcn_exp2f(sc[c4][0] - mn);
            float p1 = __builtin_amdgcn_exp2f(sc[c4][1] - mn);
            float p2 = __builtin_amdgcn_exp2f(sc[c4][2] - mn);
            float p3 = __builtin_amdgcn_exp2f(sc[c4][3] - mn);
            rs += (p0 + p1) + (p2 + p3);
            ushort4 pk;
            pk.x = f2bf(p0); pk.y = f2bf(p1); pk.z = f2bf(p2); pk.w = f2bf(p3);
            *reinterpret_cast<ushort4*>(&P[w][lc][c4 * 16 + lg * 4]) = pk;
        }
        rs += __shfl_xor(rs, 16);
        rs += __shfl_xor(rs, 32);
        ell += rs;

        // V landed on all waves before PV reads Vs
        asm volatile("s_waitcnt vmcnt(0) lgkmcnt(0)" ::: "memory");
        __builtin_amdgcn_sched_barrier(0);
        __syncthreads();

        u16x8 pf0 = *reinterpret_cast<const u16x8*>(&P[w][lc][lg * 8]);
        u16x8 pf1 = *reinterpret_cast<const u16x8*>(&P[w][lc][32 + lg * 8]);

        #pragma unroll
        for (int d8 = 0; d8 < 8; d8++) {
            const int drow = d8 * 16 + lc;
            u16x8 vf0 = *reinterpret_cast<const u16x8*>(
                VsB + drow * 128 + ((lg * 16) ^ xr));
            u16x8 vf1 = *reinterpret_cast<const u16x8*>(
                VsB + drow * 128 + ((lg * 16 + 64) ^ xr));
            oacc[d8] = mfma16(pf0, vf0, oacc[d8]);
            oacc[d8] = mfma16(pf1, vf1, oacc[d8]);
        }
        if (it + 1 < kcnt) __syncthreads();   // done reading Ks/Vs before restage
    }

    if (tau < 16) {
        float ej[4];
        #pragma unroll
        for (int j = 0; j < 4; j++)
            ej[j] = __shfl(ell, lg * 4 + j);
        #pragma unroll
        for (int d8 = 0; d8 < 8; d8++)
            #pragma unroll
            for (int j = 0; j < 4; j++) {
                float val = oacc[d8][j] / ej[j];
                o[(size_t)(q0 + lg * 4 + j) * QDIM + h * HD + d8 * 16 + lc] = f2bf(val);
            }
    } else {
        const int s = (h * 16 + (tau - 16)) * 2 + c0;
        float* po = pO + (size_t)s * 8192;
        #pragma unroll
        for (int d8 = 0; d8 < 8; d8++)
            #pragma unroll
            for (int j = 0; j < 4; j++)
                po[(w * 16 + lg * 4 + j) * 128 + d8 * 16 + lc] = oacc[d8][j];
        if (lg == 0) {
            pML[s * 128 + w * 16 + lc]      = mrow;
            pML[s * 128 + 64 + w * 16 + lc] = ell;
        }
    }
}

// ---------------------------------------------------------------------------
// K3b: combine two split-K partials (m in log2 units) -> bf16 output.
// ---------------------------------------------------------------------------
__global__ __launch_bounds__(256) void attn_combine(
    const float* __restrict__ pO,
    const float* __restrict__ pML,
    unsigned short* __restrict__ o)
{
    const int b  = blockIdx.x;
    const int h  = b >> 4, ti = b & 15;
    const int tau = 16 + ti;
    const int s0 = (h * 16 + ti) * 2, s1 = s0 + 1;

    const int tid = threadIdx.x;
    const int r   = tid >> 2;
    const int cg  = (tid & 3) * 32;

    const float m1 = pML[s0 * 128 + r],      m2 = pML[s1 * 128 + r];
    const float l1 = pML[s0 * 128 + 64 + r], l2 = pML[s1 * 128 + 64 + r];
    const float M  = fmaxf(m1, m2);
    const float w1 = __builtin_amdgcn_exp2f(m1 - M);
    const float w2 = __builtin_amdgcn_exp2f(m2 - M);
    const float rn = 1.0f / (w1 * l1 + w2 * l2);

    const float* o1 = pO + (size_t)s0 * 8192 + r * 128 + cg;
    const float* o2 = pO + (size_t)s1 * 8192 + r * 128 + cg;
    unsigned short* dst = o + (size_t)(tau * 64 + r) * QDIM + h * HD + cg;

    #pragma unroll
    for (int i = 0; i < 8; i++) {
        float4 a = *reinterpret_cast<const float4*>(o1 + i * 4);
        float4 c = *reinterpret_cast<const float4*>(o2 + i * 4);
        ushort4 pk;
        pk.x = f2bf((w1 * a.x + w2 * c.x) * rn);
        pk.y = f2bf((w1 * a.y + w2 * c.y) * rn);
        pk.z = f2bf((w1 * a.z + w2 * c.z) * rn);
        pk.w = f2bf((w1 * a.w + w2 * c.w) * rn);
        *reinterpret_cast<ushort4*>(dst + i * 4) = pk;
    }
}

// ---------------------------------------------------------------------------
extern "C" void kernel_launch(void* const* d_in, const int* in_sizes, int n_in,
                              void* d_out, int out_size, void* d_ws, size_t ws_size,
                              hipStream_t stream) {
    const float* hidden    = (const float*)d_in[0];
    const int*   positions = (const int*)d_in[1];
    const float* Wq        = (const float*)d_in[2];
    const float* Wk        = (const float*)d_in[3];
    const float* Wv        = (const float*)d_in[4];
    const float* Wo        = (const float*)d_in[5];
    float*       out       = (float*)d_out;

    char* ws = (char*)d_ws;
    // [0, 16777216)        : pO   split-K partials (attn stage)
    // [16777216, 17039360) : pML
    // [17039360, 18087936) : ctab fp32 [T][128] cos|sin (pack -> qkv gemm)
    float* pO   = (float*)(ws);
    float* pML  = (float*)(ws + 16777216);
    float* ctab = (float*)(ws + 17039360);
    unsigned short* qr  = (unsigned short*)(ws + 20971520); // 8388608 B
    unsigned short* kr  = (unsigned short*)(ws + 29360128); // 1048576 B
    unsigned short* vt  = (unsigned short*)(ws + 30408704); // 1048576 B
    unsigned short* att = (unsigned short*)(ws + 31457280); // 8388608 B
    unsigned short* hb  = (unsigned short*)(ws + 39845888); // 8388608 B
    unsigned short* Wf  = (unsigned short*)(ws + 48234496); // 10485760 B
    unsigned short* Wob = (unsigned short*)(ws + 58720256); // 8388608 B

    pack_bf16_all<<<7168, 256, 0, stream>>>(hidden, Wq, Wk, Wv, Wo, positions,
                                            hb, Wf, Wob, ctab);
    qkv_gemm_fused<<<640, 256, 0, stream>>>(hb, Wf, ctab, qr, kr, vt);
    attn_kernel<<<NH * 48, 256, 0, stream>>>(qr, kr, vt, att, pO, pML);
    attn_combine<<<256, 256, 0, stream>>>(pO, pML, att);
    gemm_out<<<512, 256, 0, stream>>>(att, Wob, out);
}